// Round 12
// baseline (85.888 us; speedup 1.0000x reference)
//
#include <hip/hip_runtime.h>
#include <math.h>

// Base = R11 (green: 85.8us, absmax 0.0). R12 change: pack every (Y,X)
// accumulator into a 2-wide vector and accumulate with
// __builtin_elementwise_fma -> v_pk_fma_f32 (VOP3P: 2 FMAs per instruction).
// Per-component math is BIT-IDENTICAL to R11 (same fma, same chain order:
// inner fma(-c,ws,acc) then fma(s,wc,acc) per half); only instruction count
// changes. Reductions use pk adds + double-shuffles, same per-component
// association. R11 showed P2's FMA stream is concentrated on SIMDs 0/1
// (~1536 issue-cyc/block); halving instruction count attacks that directly.
//
// d_ws trig layout (float2 = {cos,sin}):
//   [0,2880)    fft:   [n*288 + k]            (transposed ff_w trig)
//   [2880,3400) trig2: [ocp*130 + e*2 + (oc&1)], e = ch*16+ki*4+kj (pad 130)
//   [3400,3416) trig1: [oc*4 + e], e = a*2+c
#define FFT_OFF 0
#define W2_OFF 2880
#define W1_OFF 3400

typedef float v2f __attribute__((ext_vector_type(2)));

__device__ __forceinline__ v2f shfl_xor_v2(v2f v, int mask) {
    double d = __builtin_bit_cast(double, v);
    d = __shfl_xor(d, mask);
    return __builtin_bit_cast(v2f, d);
}
__device__ __forceinline__ v2f shfl_down_v2(v2f v, int off, int w) {
    double d = __builtin_bit_cast(double, v);
    d = __shfl_down(d, off, w);
    return __builtin_bit_cast(v2f, d);
}

__global__ void precompute_trig(const float* __restrict__ w1,
                                const float* __restrict__ w2,
                                const float* __restrict__ ff,
                                float2* __restrict__ ws) {
    int idx = blockIdx.x * blockDim.x + threadIdx.x;
    if (idx < 2880) {
        int k = idx / 10, n = idx % 10;
        float s, c; sincosf(ff[idx], &s, &c);
        ws[FFT_OFF + n * 288 + k] = make_float2(c, s);
    } else if (idx < 3392) {
        int i = idx - 2880;                  // i = oc*64 + e
        int oc = i >> 6, e = i & 63;
        float s, c; sincosf(w2[i], &s, &c);
        ws[W2_OFF + (oc >> 1) * 130 + e * 2 + (oc & 1)] = make_float2(c, s);
    } else if (idx < 3408) {
        int i = idx - 3392;
        float s, c; sincosf(w1[i], &s, &c);
        ws[W1_OFF + i] = make_float2(c, s);
    }
}

// 320 threads = 5 waves, 1 image/block, 4096 blocks.
// LDS: trig2 520f2 + sc1 1008f2 + sc2 288f2 = 14.5KB.
__global__ __launch_bounds__(320) void ringnn_kernel(
    const float* __restrict__ x,
    const float2* __restrict__ ws,
    float* __restrict__ out)
{
    __shared__ __align__(16) float2 trig2[520];
    __shared__ __align__(16) float2 sc1[1008];  // ch*252 + row*18 + col
    __shared__ __align__(16) float2 sc2[288];   // p*8 + oc
    const int tid = threadIdx.x;
    const float2* __restrict__ fft = ws + FFT_OFF;
    const float2* __restrict__ w1t = ws + W1_OFF;

    // ---- hoisted x loads (latency hides behind trig2 staging) ----
    int pi = (tid % 196) / 14, pj = tid % 14;
    float2 r0 = make_float2(0.f, 0.f), r1 = make_float2(0.f, 0.f);
    if (tid < 196) {
        const float* xb = x + (size_t)blockIdx.x * 784;
        r0 = *(const float2*)(xb + (2 * pi) * 28 + 2 * pj);
        r1 = *(const float2*)(xb + (2 * pi + 1) * 28 + 2 * pj);
    }

    // ---- stage trig2 from ws: pure b128 copies, no sincos ----
    if (tid < 260) ((float4*)trig2)[tid] = ((const float4*)(ws + W2_OFF))[tid];

    // ---- phase 1: ring conv1 (2x2 stride 2), thread = pos ----
    // trig1 via wave-uniform global -> scalar loads; acc = v2f (Y,X).
    if (tid < 196) {
        float sx[4], cx[4];
        __sincosf(r0.x, &sx[0], &cx[0]);
        __sincosf(r0.y, &sx[1], &cx[1]);
        __sincosf(r1.x, &sx[2], &cx[2]);
        __sincosf(r1.y, &sx[3], &cx[3]);
        #pragma unroll
        for (int oc = 0; oc < 4; oc++) {
            float4 wa = *(const float4*)(w1t + oc * 4);      // (c0,s0,c1,s1)
            float4 wb = *(const float4*)(w1t + oc * 4 + 2);  // (c2,s2,c3,s3)
            v2f A = {0.f, 0.f};                              // (Y, X)
            A = __builtin_elementwise_fma((v2f){-cx[0], sx[0]}, (v2f){wa.y, wa.y}, A);
            A = __builtin_elementwise_fma((v2f){ sx[0], cx[0]}, (v2f){wa.x, wa.x}, A);
            A = __builtin_elementwise_fma((v2f){-cx[1], sx[1]}, (v2f){wa.w, wa.w}, A);
            A = __builtin_elementwise_fma((v2f){ sx[1], cx[1]}, (v2f){wa.z, wa.z}, A);
            A = __builtin_elementwise_fma((v2f){-cx[2], sx[2]}, (v2f){wb.y, wb.y}, A);
            A = __builtin_elementwise_fma((v2f){ sx[2], cx[2]}, (v2f){wb.x, wb.x}, A);
            A = __builtin_elementwise_fma((v2f){-cx[3], sx[3]}, (v2f){wb.w, wb.w}, A);
            A = __builtin_elementwise_fma((v2f){ sx[3], cx[3]}, (v2f){wb.z, wb.z}, A);
            float Y = A.x, X = A.y;
            float inv = rsqrtf(fmaxf(fmaf(X, X, Y * Y), 1e-30f));
            sc1[oc * 252 + pi * 18 + pj] = make_float2(Y * inv, X * inv);
        }
    }
    __syncthreads();   // single barrier: covers trig2 staging AND sc1 writes

    // ---- phase 2: ring conv2 (4x4 stride 2) ----
    // thread = (oi, ojg, ocp, hf); acc a[ojl][ocpar] = v2f (Y,X).
    if (tid < 96) {
        int r = tid;
        int oi = r >> 4, ojg = (r >> 3) & 1, ocp = (r >> 1) & 3, hf = r & 1;
        const float2* wbp = trig2 + ocp * 130;
        v2f a[3][2] = {{{0.f,0.f},{0.f,0.f}},{{0.f,0.f},{0.f,0.f}},{{0.f,0.f},{0.f,0.f}}};
        #pragma unroll
        for (int ch = 0; ch < 4; ch++) {
            #pragma unroll
            for (int kk = 0; kk < 2; kk++) {
                int ki = hf * 2 + kk;
                int base = ch * 252 + (oi * 2 + ki) * 18 + ojg * 6;
                float4 f0 = *(const float4*)(sc1 + base);
                float4 f1 = *(const float4*)(sc1 + base + 2);
                float4 f2 = *(const float4*)(sc1 + base + 4);
                float4 f3 = *(const float4*)(sc1 + base + 6);
                v2f scp[8] = {{f0.x,f0.y},{f0.z,f0.w},{f1.x,f1.y},{f1.z,f1.w},
                              {f2.x,f2.y},{f2.z,f2.w},{f3.x,f3.y},{f3.z,f3.w}};
                int e0 = ch * 16 + ki * 4;
                #pragma unroll
                for (int kj = 0; kj < 4; kj++) {
                    float4 wv = *(const float4*)(wbp + (e0 + kj) * 2); // (c0,s0,c1,s1)
                    #pragma unroll
                    for (int ojl = 0; ojl < 3; ojl++) {
                        v2f sc = scp[ojl * 2 + kj];        // (s, c)
                        v2f msc = {-sc.y, sc.x};           // (-c, s)
                        a[ojl][0] = __builtin_elementwise_fma(msc, (v2f){wv.y, wv.y}, a[ojl][0]);
                        a[ojl][0] = __builtin_elementwise_fma(sc,  (v2f){wv.x, wv.x}, a[ojl][0]);
                        a[ojl][1] = __builtin_elementwise_fma(msc, (v2f){wv.w, wv.w}, a[ojl][1]);
                        a[ojl][1] = __builtin_elementwise_fma(sc,  (v2f){wv.z, wv.z}, a[ojl][1]);
                    }
                }
            }
        }
        #pragma unroll
        for (int ojl = 0; ojl < 3; ojl++) {
            v2f a0 = a[ojl][0]; a0 += shfl_xor_v2(a[ojl][0], 1);
            v2f a1 = a[ojl][1]; a1 += shfl_xor_v2(a[ojl][1], 1);
            v2f A = hf ? a1 : a0;
            float Y = A.x, X = A.y;
            float inv = rsqrtf(fmaxf(fmaf(X, X, Y * Y), 1e-30f));
            int p = oi * 6 + ojg * 3 + ojl;
            sc2[p * 8 + ocp * 2 + hf] = make_float2(Y * inv, X * inv);
        }
    }
    __syncthreads();

    // ---- phase 3: ring feed-forward; thread = (n, s32); acc v2f (Y,X) ----
    {
        int n = tid >> 5, s = tid & 31;
        const float2* wn = fft + n * 288;
        v2f A = {0.f, 0.f};
        #pragma unroll
        for (int i = 0; i < 9; i++) {
            int k = i * 32 + s;
            float2 sc = sc2[k];                // (s, c)
            float2 w = wn[k];                  // (c, s)
            A = __builtin_elementwise_fma((v2f){-sc.y, sc.x}, (v2f){w.y, w.y}, A);
            A = __builtin_elementwise_fma((v2f){ sc.x, sc.y}, (v2f){w.x, w.x}, A);
        }
        #pragma unroll
        for (int off = 16; off > 0; off >>= 1)
            A += shfl_down_v2(A, off, 32);
        if (s == 0) {
            float Y = A.x, X = A.y;
            out[(size_t)blockIdx.x * 10 + n] =
                Y * rsqrtf(fmaxf(fmaf(X, X, Y * Y), 1e-30f));
        }
    }
}

extern "C" void kernel_launch(void* const* d_in, const int* in_sizes, int n_in,
                              void* d_out, int out_size, void* d_ws, size_t ws_size,
                              hipStream_t stream) {
    const float* x  = (const float*)d_in[0];
    const float* w1 = (const float*)d_in[1];
    const float* w2 = (const float*)d_in[2];
    const float* ff = (const float*)d_in[3];
    float* out = (float*)d_out;
    const int B = in_sizes[0] / 784;   // 4096

    float2* ws = (float2*)d_ws;
    precompute_trig<<<14, 256, 0, stream>>>(w1, w2, ff, ws);
    ringnn_kernel<<<B, 320, 0, stream>>>(x, ws, out);
}